// Round 1
// baseline (4813.742 us; speedup 1.0000x reference)
//
#include <hip/hip_runtime.h>

// RNN_Model: bidirectional 2-layer LSTM (T=300,B=4096,D=39,H1=35,H2=30) + FC(50,40,2)
// Round 1: fp32 VALU implementation.
//   lstm_l1: grid (128 tiles, 2 dirs), 256 thr, 32 batch rows/block, all 300 steps in-block.
//   lstm_l2: same shape, consumes h1 from ws.
//   fc:      one thread per (b,t) row, uniform scalar weight loads.

#define T_STEPS 300
#define DIN 39
#define H1 35
#define H2 30
#define BATCH 4096
#define ROWS 32
#define K1 (DIN + H1)   // 74
#define K2 (H1 + H2)    // 65
#define XH1_STR 77      // odd stride -> conflict-free LDS gather
#define XH2_STR 67
#define NU1 5           // units per group, layer 1 (8 groups x 5 = 40, pad >=35)
#define J1 20           // 4 gates * NU1
#define NU2 4           // layer 2: 8 groups x 4 = 32, pad >=30
#define J2 16
#define FC1N 50
#define FC2N 40

__device__ __forceinline__ float sigf(float x) {
    return __builtin_amdgcn_rcpf(1.0f + __expf(-x));
}
__device__ __forceinline__ float tanh_f(float x) {
    // tanh(x) = 1 - 2/(1+e^{2x}); graceful at +/-inf
    return 1.0f - 2.0f * __builtin_amdgcn_rcpf(1.0f + __expf(2.0f * x));
}

__global__ __launch_bounds__(256) void lstm_l1(
    const float* __restrict__ x,
    const float* __restrict__ fw_W1, const float* __restrict__ fw_b1,
    const float* __restrict__ bw_W1, const float* __restrict__ bw_b1,
    float* __restrict__ h1out)
{
    const int tid = threadIdx.x;
    const int r   = tid & 31;
    const int ug  = tid >> 5;           // 0..7, wave-half uniform
    const int b0  = blockIdx.x * ROWS;
    const int dir = blockIdx.y;
    const float* W  = dir ? bw_W1 : fw_W1;
    const float* bb = dir ? bw_b1 : fw_b1;

    __shared__ __align__(16) float Wr[K1 * 8 * J1];   // 74*160*4 = 47360 B
    __shared__ __align__(16) float br[8 * J1];
    __shared__ float xh[ROWS * XH1_STR];              // 9856 B

    // Reorder W: Wr[k][ug][g*NU1+du] = W[k][g*H1 + (ug*NU1+du)], pad with 0
    for (int idx = tid; idx < K1 * 8 * J1; idx += 256) {
        int k = idx / (8 * J1);
        int q = idx % (8 * J1);
        int g2 = q / J1, j = q % J1;
        int g = j / NU1, du = j % NU1;
        int u = g2 * NU1 + du;
        Wr[idx] = (u < H1) ? W[k * (4 * H1) + g * H1 + u] : 0.0f;
    }
    for (int idx = tid; idx < 8 * J1; idx += 256) {
        int g2 = idx / J1, j = idx % J1;
        int g = j / NU1, du = j % NU1;
        int u = g2 * NU1 + du;
        br[idx] = (u < H1) ? bb[g * H1 + u] : 0.0f;
    }
    for (int idx = tid; idx < ROWS * XH1_STR; idx += 256) xh[idx] = 0.0f;
    __syncthreads();

    float c[NU1] = {0.f, 0.f, 0.f, 0.f, 0.f};
    const int u0 = ug * NU1;

    for (int s = 0; s < T_STEPS; ++s) {
        const int tt = dir ? (T_STEPS - 1 - s) : s;
        // stage x_t tile into xh[.][0:39]
        for (int idx = tid; idx < ROWS * DIN; idx += 256) {
            int rr = idx / DIN, kk = idx % DIN;
            xh[rr * XH1_STR + kk] = x[((size_t)(b0 + rr) * T_STEPS + tt) * DIN + kk];
        }
        __syncthreads();

        float acc[J1];
        #pragma unroll
        for (int j = 0; j < J1; ++j) acc[j] = br[ug * J1 + j];

        #pragma unroll 2
        for (int k = 0; k < K1; ++k) {
            float xv = xh[r * XH1_STR + k];
            const float4* wp = (const float4*)&Wr[(k * 8 + ug) * J1];
            #pragma unroll
            for (int v = 0; v < 5; ++v) {
                float4 w = wp[v];
                acc[4 * v + 0] += xv * w.x;
                acc[4 * v + 1] += xv * w.y;
                acc[4 * v + 2] += xv * w.z;
                acc[4 * v + 3] += xv * w.w;
            }
        }
        __syncthreads();   // all xh reads done before h writes

        #pragma unroll
        for (int du = 0; du < NU1; ++du) {
            int u = u0 + du;
            float zi = acc[0 * NU1 + du];
            float zj = acc[1 * NU1 + du];
            float zf = acc[2 * NU1 + du];
            float zo = acc[3 * NU1 + du];
            float cc = sigf(zf + 1.0f) * c[du] + sigf(zi) * tanh_f(zj);
            float hh = sigf(zo) * tanh_f(cc);
            c[du] = cc;
            if (u < H1) {
                xh[r * XH1_STR + DIN + u] = hh;
                h1out[((size_t)(dir * T_STEPS + s) * BATCH + (b0 + r)) * H1 + u] = hh;
            }
        }
        __syncthreads();
    }
}

__global__ __launch_bounds__(256) void lstm_l2(
    const float* __restrict__ h1,
    const float* __restrict__ fw_W2, const float* __restrict__ fw_b2,
    const float* __restrict__ bw_W2, const float* __restrict__ bw_b2,
    float* __restrict__ h2out)
{
    const int tid = threadIdx.x;
    const int r   = tid & 31;
    const int ug  = tid >> 5;
    const int b0  = blockIdx.x * ROWS;
    const int dir = blockIdx.y;
    const float* W  = dir ? bw_W2 : fw_W2;
    const float* bb = dir ? bw_b2 : fw_b2;

    __shared__ __align__(16) float Wr[K2 * 8 * J2];   // 65*128*4 = 33280 B
    __shared__ __align__(16) float br[8 * J2];
    __shared__ float xh[ROWS * XH2_STR];              // 8576 B

    for (int idx = tid; idx < K2 * 8 * J2; idx += 256) {
        int k = idx / (8 * J2);
        int q = idx % (8 * J2);
        int g2 = q / J2, j = q % J2;
        int g = j / NU2, du = j % NU2;
        int u = g2 * NU2 + du;
        Wr[idx] = (u < H2) ? W[k * (4 * H2) + g * H2 + u] : 0.0f;
    }
    for (int idx = tid; idx < 8 * J2; idx += 256) {
        int g2 = idx / J2, j = idx % J2;
        int g = j / NU2, du = j % NU2;
        int u = g2 * NU2 + du;
        br[idx] = (u < H2) ? bb[g * H2 + u] : 0.0f;
    }
    for (int idx = tid; idx < ROWS * XH2_STR; idx += 256) xh[idx] = 0.0f;
    __syncthreads();

    float c[NU2] = {0.f, 0.f, 0.f, 0.f};
    const int u0 = ug * NU2;

    for (int s = 0; s < T_STEPS; ++s) {
        // stage h1 step tile into xh[.][0:35]
        for (int idx = tid; idx < ROWS * H1; idx += 256) {
            int rr = idx / H1, kk = idx % H1;
            xh[rr * XH2_STR + kk] =
                h1[((size_t)(dir * T_STEPS + s) * BATCH + (b0 + rr)) * H1 + kk];
        }
        __syncthreads();

        float acc[J2];
        #pragma unroll
        for (int j = 0; j < J2; ++j) acc[j] = br[ug * J2 + j];

        #pragma unroll 2
        for (int k = 0; k < K2; ++k) {
            float xv = xh[r * XH2_STR + k];
            const float4* wp = (const float4*)&Wr[(k * 8 + ug) * J2];
            #pragma unroll
            for (int v = 0; v < 4; ++v) {
                float4 w = wp[v];
                acc[4 * v + 0] += xv * w.x;
                acc[4 * v + 1] += xv * w.y;
                acc[4 * v + 2] += xv * w.z;
                acc[4 * v + 3] += xv * w.w;
            }
        }
        __syncthreads();

        const int tt = dir ? (T_STEPS - 1 - s) : s;
        #pragma unroll
        for (int du = 0; du < NU2; ++du) {
            int u = u0 + du;
            float zi = acc[0 * NU2 + du];
            float zj = acc[1 * NU2 + du];
            float zf = acc[2 * NU2 + du];
            float zo = acc[3 * NU2 + du];
            float cc = sigf(zf + 1.0f) * c[du] + sigf(zi) * tanh_f(zj);
            float hh = sigf(zo) * tanh_f(cc);
            c[du] = cc;
            if (u < H2) {
                xh[r * XH2_STR + H1 + u] = hh;
                h2out[((size_t)(dir * T_STEPS + tt) * BATCH + (b0 + r)) * H2 + u] = hh;
            }
        }
        __syncthreads();
    }
}

__global__ __launch_bounds__(256) void fc_kernel(
    const float* __restrict__ h2fw, const float* __restrict__ h2bw,
    const float* __restrict__ Wf1, const float* __restrict__ bf1,
    const float* __restrict__ Wf2, const float* __restrict__ bf2,
    const float* __restrict__ Wo,  const float* __restrict__ bo,
    float* __restrict__ out)
{
    const int row = blockIdx.x * 256 + threadIdx.x;  // 0..1228799
    const int b = row & (BATCH - 1);
    const int t = row >> 12;

    float h[2 * H2];
    const float* pf = &h2fw[((size_t)t * BATCH + b) * H2];
    const float* pb = &h2bw[((size_t)t * BATCH + b) * H2];
    #pragma unroll
    for (int k = 0; k < H2; ++k) { h[k] = pf[k]; h[H2 + k] = pb[k]; }

    float a1[FC1N];
    #pragma unroll 2
    for (int j = 0; j < FC1N; ++j) {
        float acc = bf1[j];
        #pragma unroll
        for (int k = 0; k < 2 * H2; ++k) acc += h[k] * Wf1[k * FC1N + j];
        a1[j] = fmaxf(acc, 0.0f);
    }

    float a2[FC2N];
    #pragma unroll 2
    for (int j = 0; j < FC2N; ++j) {
        float acc = bf2[j];
        #pragma unroll
        for (int k = 0; k < FC1N; ++k) acc += a1[k] * Wf2[k * FC2N + j];
        a2[j] = fmaxf(acc, 0.0f);
    }

    float o0 = bo[0], o1 = bo[1];
    #pragma unroll
    for (int k = 0; k < FC2N; ++k) {
        o0 += a2[k] * Wo[2 * k + 0];
        o1 += a2[k] * Wo[2 * k + 1];
    }
    out[((size_t)b * T_STEPS + t) * 2 + 0] = o0;
    out[((size_t)b * T_STEPS + t) * 2 + 1] = o1;
}

extern "C" void kernel_launch(void* const* d_in, const int* in_sizes, int n_in,
                              void* d_out, int out_size, void* d_ws, size_t ws_size,
                              hipStream_t stream) {
    const float* x     = (const float*)d_in[0];
    const float* fw_W1 = (const float*)d_in[1];
    const float* fw_b1 = (const float*)d_in[2];
    const float* fw_W2 = (const float*)d_in[3];
    const float* fw_b2 = (const float*)d_in[4];
    const float* bw_W1 = (const float*)d_in[5];
    const float* bw_b1 = (const float*)d_in[6];
    const float* bw_W2 = (const float*)d_in[7];
    const float* bw_b2 = (const float*)d_in[8];
    const float* Wf1   = (const float*)d_in[9];
    const float* bf1   = (const float*)d_in[10];
    const float* Wf2   = (const float*)d_in[11];
    const float* bf2   = (const float*)d_in[12];
    const float* Wo    = (const float*)d_in[13];
    const float* bo    = (const float*)d_in[14];
    float* outp = (float*)d_out;

    // workspace: h1 [2][300][4096][35] fp32, then h2 [2][300][4096][30] fp32
    float* h1 = (float*)d_ws;                                   // 344,064,000 B
    float* h2 = h1 + (size_t)2 * T_STEPS * BATCH * H1;          // 294,912,000 B

    dim3 gl(BATCH / ROWS, 2);   // (128, 2)
    lstm_l1<<<gl, 256, 0, stream>>>(x, fw_W1, fw_b1, bw_W1, bw_b1, h1);
    lstm_l2<<<gl, 256, 0, stream>>>(h1, fw_W2, fw_b2, bw_W2, bw_b2, h2);

    const float* h2fw = h2;
    const float* h2bw = h2 + (size_t)T_STEPS * BATCH * H2;
    fc_kernel<<<(BATCH * T_STEPS) / 256, 256, 0, stream>>>(
        h2fw, h2bw, Wf1, bf1, Wf2, bf2, Wo, bo, outp);
}

// Round 3
// 1289.943 us; speedup vs baseline: 3.7317x; 3.7317x over previous
//
#include <hip/hip_runtime.h>

// RNN_Model: biLSTM (T=300,B=4096,D=39,H1=35,H2=30) + FC(50,40,2)
// Round 3: round-2 fp16-MFMA fused LSTM + RACE FIX: __syncthreads() between LDS
// zero-init and prologue x(0) staging (write-write race on ap1[0,40) caused
// nondeterministic replay failure in round 2).
//  - xprep: x -> [T][B][40] fp16 (coalesced per-step staging)
//  - wprep: weights -> MFMA B-fragments (K packed: L1 x[0,40)|h1[40,75); L2 h1[0,36)|h2[36,66))
//  - lstm_fused: 256 blocks (128 row-tiles x 2 dirs) x 384 thr; 32 rows/block over 300 steps;
//      per layer 9 mfma_f32_16x16x32_f16 per wave; weights persistent in VGPRs;
//      z via LDS (col-major, stride 36) for fp32 nonlinearity; c-state in regs; 4 barriers/step.
//  - fc: fp32, thread per (b,t); weight loads uniform -> s_load.

#define T_STEPS 300
#define DIN 39
#define H1 35
#define H2 30
#define BATCH 4096
#define FC1N 50
#define FC2N 40

#define AP_STR 104       // halfs per A-panel row (quad-stride 13 -> conflict-free b128)
#define ZL_STR 36        // f32 per z column (32 rows + 4 pad, odd quad-stride)

typedef _Float16 f16;
typedef _Float16 half8 __attribute__((ext_vector_type(8)));
typedef float floatx4 __attribute__((ext_vector_type(4)));

__device__ __forceinline__ float sigf(float x) {
    return __builtin_amdgcn_rcpf(1.0f + __expf(-x));
}
__device__ __forceinline__ float tanh_f(float x) {
    return 1.0f - 2.0f * __builtin_amdgcn_rcpf(1.0f + __expf(2.0f * x));
}

// ---------------- xprep: x[B][T][39] f32 -> xp[T][B][40] f16 (slot 39 = 0) -------------
__global__ __launch_bounds__(256) void xprep_kernel(const float* __restrict__ x,
                                                    f16* __restrict__ xp) {
    size_t idx = (size_t)blockIdx.x * 256 + threadIdx.x;   // total 300*4096*40
    int k = (int)(idx % 40);
    size_t tr = idx / 40;
    int r = (int)(tr % BATCH);
    int t = (int)(tr / BATCH);
    float v = (k < DIN) ? x[((size_t)r * T_STEPS + t) * DIN + k] : 0.0f;
    xp[idx] = (f16)v;
}

// ---------------- wprep: build MFMA B-fragments -----------------------------------------
// frag = ((dir*2+layer)*3 + cg)*9 + tile*3 + chunk ; lane holds B[k=oct*8+j][n=lane&15]
__global__ void wprep_kernel(const float* __restrict__ fw1, const float* __restrict__ bw1,
                             const float* __restrict__ fw2, const float* __restrict__ bw2,
                             f16* __restrict__ bp) {
    int frag = blockIdx.x;        // 0..107
    int lane = threadIdx.x;       // 0..63
    int chunk = frag % 3;
    int tile  = (frag / 3) % 3;
    int cg    = (frag / 9) % 3;
    int layer = (frag / 27) % 2;
    int dir   = frag / 54;
    const float* W = (layer == 0) ? (dir ? bw1 : fw1) : (dir ? bw2 : fw2);
    int col = cg * 48 + tile * 16 + (lane & 15);
    int g = col / 36, u = col % 36;
    for (int j = 0; j < 8; ++j) {
        int k = chunk * 32 + (lane >> 4) * 8 + j;
        float v = 0.0f;
        if (layer == 0) {
            if (u < H1) {
                int ok = -1;
                if (k < 39) ok = k;                       // x rows 0..38
                else if (k >= 40 && k < 75) ok = k - 1;   // h rows 39..73
                if (ok >= 0) v = W[ok * (4 * H1) + g * H1 + u];
            }
        } else {
            if (u < H2) {
                int ok = -1;
                if (k < 35) ok = k;                       // h1 rows 0..34
                else if (k >= 36 && k < 66) ok = k - 1;   // h2 rows 35..64
                if (ok >= 0) v = W[ok * (4 * H2) + g * H2 + u];
            }
        }
        bp[(size_t)frag * 512 + lane * 8 + j] = (f16)v;
    }
}

// ---------------- fused 2-layer LSTM -----------------------------------------------------
__global__ __launch_bounds__(384) void lstm_fused(
    const f16* __restrict__ xp, const f16* __restrict__ bp,
    const float* __restrict__ fb1, const float* __restrict__ bb1,
    const float* __restrict__ fb2, const float* __restrict__ bb2,
    f16* __restrict__ h2s)
{
    __shared__ f16 ap1[32 * AP_STR];     // L1 panel: x [0,40) | h1 [40,75) | 0 [75,96)
    __shared__ f16 ap2[32 * AP_STR];     // L2 panel: h1 [0,35) | 0 | h2 [36,66) | 0 [66,96)
    __shared__ float zl[144 * ZL_STR];   // z exchange, col-major

    const int tid = threadIdx.x;
    const int b0  = blockIdx.x * 32;
    const int dir = blockIdx.y;
    const int wv   = tid >> 6;
    const int lane = tid & 63;
    const int cg = wv % 3;               // col group: cols cg*48 .. +47
    const int rh = wv / 3;               // row half: rows rh*16 .. +15
    const int lm = lane & 15;
    const int oct = lane >> 4;
    const float* b1 = dir ? bb1 : fb1;
    const float* b2 = dir ? bb2 : fb2;

    // persistent weight B-fragments
    half8 bf[2][3][3];
    #pragma unroll
    for (int layer = 0; layer < 2; ++layer)
        #pragma unroll
        for (int tile = 0; tile < 3; ++tile)
            #pragma unroll
            for (int chunk = 0; chunk < 3; ++chunk) {
                int frag = ((dir * 2 + layer) * 3 + cg) * 9 + tile * 3 + chunk;
                bf[layer][tile][chunk] = *(const half8*)(bp + (size_t)frag * 512 + lane * 8);
            }

    // nonlinearity work items: it = tid + 384*i -> (row = it&31, u = it>>5), u in [0,36)
    int itr[3], itu[3];
    float bs1[3][4], bs2[3][4];
    #pragma unroll
    for (int i = 0; i < 3; ++i) {
        int it = tid + 384 * i;
        itr[i] = it & 31; itu[i] = it >> 5;
        int u = itu[i];
        #pragma unroll
        for (int g = 0; g < 4; ++g) {
            bs1[i][g] = (u < H1) ? b1[g * H1 + u] : 0.0f;
            bs2[i][g] = (u < H2) ? b2[g * H2 + u] : 0.0f;
        }
    }
    float c1s[3] = {0.f, 0.f, 0.f}, c2s[3] = {0.f, 0.f, 0.f};

    // zero panels (h0 = 0, zero-pad K regions)
    for (int idx = tid; idx < 32 * AP_STR; idx += 384) { ap1[idx] = (f16)0.f; ap2[idx] = (f16)0.f; }
    __syncthreads();   // RACE FIX: zero-init must complete before x(0) staging below

    // prologue: stage x(0), prefetch x(1)
    uint2 xa = make_uint2(0u, 0u);
    const int xr = tid / 10, xq = tid % 10;
    if (tid < 320) {
        int t0 = dir ? (T_STEPS - 1) : 0;
        uint2 v = *(const uint2*)(xp + ((size_t)t0 * BATCH + b0 + xr) * 40 + xq * 4);
        *(uint2*)(ap1 + xr * AP_STR + xq * 4) = v;
        int t1 = dir ? (T_STEPS - 2) : 1;
        xa = *(const uint2*)(xp + ((size_t)t1 * BATCH + b0 + xr) * 40 + xq * 4);
    }
    __syncthreads();

    const int arow = (rh * 16 + lm) * AP_STR + oct * 8;

    for (int s = 0; s < T_STEPS; ++s) {
        // ---- L1 MFMA ----
        {
            half8 a0 = *(const half8*)(ap1 + arow);
            half8 a1 = *(const half8*)(ap1 + arow + 32);
            half8 a2 = *(const half8*)(ap1 + arow + 64);
            floatx4 C0 = {0.f,0.f,0.f,0.f}, C1 = C0, C2 = C0;
            C0 = __builtin_amdgcn_mfma_f32_16x16x32_f16(a0, bf[0][0][0], C0, 0, 0, 0);
            C1 = __builtin_amdgcn_mfma_f32_16x16x32_f16(a0, bf[0][1][0], C1, 0, 0, 0);
            C2 = __builtin_amdgcn_mfma_f32_16x16x32_f16(a0, bf[0][2][0], C2, 0, 0, 0);
            C0 = __builtin_amdgcn_mfma_f32_16x16x32_f16(a1, bf[0][0][1], C0, 0, 0, 0);
            C1 = __builtin_amdgcn_mfma_f32_16x16x32_f16(a1, bf[0][1][1], C1, 0, 0, 0);
            C2 = __builtin_amdgcn_mfma_f32_16x16x32_f16(a1, bf[0][2][1], C2, 0, 0, 0);
            C0 = __builtin_amdgcn_mfma_f32_16x16x32_f16(a2, bf[0][0][2], C0, 0, 0, 0);
            C1 = __builtin_amdgcn_mfma_f32_16x16x32_f16(a2, bf[0][1][2], C1, 0, 0, 0);
            C2 = __builtin_amdgcn_mfma_f32_16x16x32_f16(a2, bf[0][2][2], C2, 0, 0, 0);
            int zb = rh * 16 + oct * 4;
            *(floatx4*)(zl + (cg * 48 + 0 * 16 + lm) * ZL_STR + zb) = C0;
            *(floatx4*)(zl + (cg * 48 + 1 * 16 + lm) * ZL_STR + zb) = C1;
            *(floatx4*)(zl + (cg * 48 + 2 * 16 + lm) * ZL_STR + zb) = C2;
        }
        __syncthreads();   // (2) z1 ready; A1 reads done

        // stage x(s+1) into ap1, prefetch x(s+2)
        if (tid < 320 && s + 1 < T_STEPS) {
            *(uint2*)(ap1 + xr * AP_STR + xq * 4) = xa;
            if (s + 2 < T_STEPS) {
                int t2 = dir ? (T_STEPS - 1 - (s + 2)) : (s + 2);
                xa = *(const uint2*)(xp + ((size_t)t2 * BATCH + b0 + xr) * 40 + xq * 4);
            }
        }

        // ---- nonlinearity L1 -> h1 into ap1 (next step) and ap2 (now) ----
        #pragma unroll
        for (int i = 0; i < 3; ++i) {
            int row = itr[i], u = itu[i];
            float zi = zl[(0 * 36 + u) * ZL_STR + row] + bs1[i][0];
            float zj = zl[(1 * 36 + u) * ZL_STR + row] + bs1[i][1];
            float zf = zl[(2 * 36 + u) * ZL_STR + row] + bs1[i][2];
            float zo = zl[(3 * 36 + u) * ZL_STR + row] + bs1[i][3];
            float cc = sigf(zf + 1.0f) * c1s[i] + sigf(zi) * tanh_f(zj);
            c1s[i] = cc;
            float hh = sigf(zo) * tanh_f(cc);
            if (u < H1) {
                f16 hv = (f16)hh;
                ap1[row * AP_STR + 40 + u] = hv;
                ap2[row * AP_STR + u] = hv;
            }
        }
        __syncthreads();   // (3) h1 ready; z1 reads done; x(s+1) staged

        // ---- L2 MFMA ----
        {
            half8 a0 = *(const half8*)(ap2 + arow);
            half8 a1 = *(const half8*)(ap2 + arow + 32);
            half8 a2 = *(const half8*)(ap2 + arow + 64);
            floatx4 C0 = {0.f,0.f,0.f,0.f}, C1 = C0, C2 = C0;
            C0 = __builtin_amdgcn_mfma_f32_16x16x32_f16(a0, bf[1][0][0], C0, 0, 0, 0);
            C1 = __builtin_amdgcn_mfma_f32_16x16x32_f16(a0, bf[1][1][0], C1, 0, 0, 0);
            C2 = __builtin_amdgcn_mfma_f32_16x16x32_f16(a0, bf[1][2][0], C2, 0, 0, 0);
            C0 = __builtin_amdgcn_mfma_f32_16x16x32_f16(a1, bf[1][0][1], C0, 0, 0, 0);
            C1 = __builtin_amdgcn_mfma_f32_16x16x32_f16(a1, bf[1][1][1], C1, 0, 0, 0);
            C2 = __builtin_amdgcn_mfma_f32_16x16x32_f16(a1, bf[1][2][1], C2, 0, 0, 0);
            C0 = __builtin_amdgcn_mfma_f32_16x16x32_f16(a2, bf[1][0][2], C0, 0, 0, 0);
            C1 = __builtin_amdgcn_mfma_f32_16x16x32_f16(a2, bf[1][1][2], C1, 0, 0, 0);
            C2 = __builtin_amdgcn_mfma_f32_16x16x32_f16(a2, bf[1][2][2], C2, 0, 0, 0);
            int zb = rh * 16 + oct * 4;
            *(floatx4*)(zl + (cg * 48 + 0 * 16 + lm) * ZL_STR + zb) = C0;
            *(floatx4*)(zl + (cg * 48 + 1 * 16 + lm) * ZL_STR + zb) = C1;
            *(floatx4*)(zl + (cg * 48 + 2 * 16 + lm) * ZL_STR + zb) = C2;
        }
        __syncthreads();   // (4) z2 ready

        // ---- nonlinearity L2 -> h2 into ap2 ----
        #pragma unroll
        for (int i = 0; i < 3; ++i) {
            int row = itr[i], u = itu[i];
            float zi = zl[(0 * 36 + u) * ZL_STR + row] + bs2[i][0];
            float zj = zl[(1 * 36 + u) * ZL_STR + row] + bs2[i][1];
            float zf = zl[(2 * 36 + u) * ZL_STR + row] + bs2[i][2];
            float zo = zl[(3 * 36 + u) * ZL_STR + row] + bs2[i][3];
            float cc = sigf(zf + 1.0f) * c2s[i] + sigf(zi) * tanh_f(zj);
            c2s[i] = cc;
            float hh = sigf(zo) * tanh_f(cc);
            if (u < H2) ap2[row * AP_STR + 36 + u] = (f16)hh;
        }
        __syncthreads();   // (5) h2 ready

        // ---- copy h2 tile out (coalesced; reads [36,68) incl 2 zero pads) ----
        {
            int t_out = dir ? (T_STEPS - 1 - s) : s;
            size_t base = (((size_t)dir * T_STEPS + t_out) * BATCH + b0) * 32;
            for (int idx = tid; idx < 512; idx += 384) {
                int row = idx >> 4, up = idx & 15;
                unsigned v = *(const unsigned*)(ap2 + row * AP_STR + 36 + up * 2);
                *(unsigned*)(h2s + base + (size_t)row * 32 + up * 2) = v;
            }
        }
    }
}

// ---------------- FC stack (fp32) --------------------------------------------------------
__global__ __launch_bounds__(256) void fc_kernel(
    const f16* __restrict__ h2s,
    const float* __restrict__ Wf1, const float* __restrict__ bf1,
    const float* __restrict__ Wf2, const float* __restrict__ bf2,
    const float* __restrict__ Wo,  const float* __restrict__ bo,
    float* __restrict__ out)
{
    const int row = blockIdx.x * 256 + threadIdx.x;  // 0..1228799
    const int b = row & (BATCH - 1);
    const int t = row >> 12;

    float h[2 * H2];
    const f16* pf = h2s + (((size_t)0 * T_STEPS + t) * BATCH + b) * 32;
    const f16* pb = h2s + (((size_t)1 * T_STEPS + t) * BATCH + b) * 32;
    #pragma unroll
    for (int k = 0; k < H2; ++k) { h[k] = (float)pf[k]; h[H2 + k] = (float)pb[k]; }

    float a1[FC1N];
    #pragma unroll 2
    for (int j = 0; j < FC1N; ++j) {
        float acc = bf1[j];
        #pragma unroll
        for (int k = 0; k < 2 * H2; ++k) acc += h[k] * Wf1[k * FC1N + j];
        a1[j] = fmaxf(acc, 0.0f);
    }
    float a2[FC2N];
    #pragma unroll 2
    for (int j = 0; j < FC2N; ++j) {
        float acc = bf2[j];
        #pragma unroll
        for (int k = 0; k < FC1N; ++k) acc += a1[k] * Wf2[k * FC2N + j];
        a2[j] = fmaxf(acc, 0.0f);
    }
    float o0 = bo[0], o1 = bo[1];
    #pragma unroll
    for (int k = 0; k < FC2N; ++k) {
        o0 += a2[k] * Wo[2 * k + 0];
        o1 += a2[k] * Wo[2 * k + 1];
    }
    out[((size_t)b * T_STEPS + t) * 2 + 0] = o0;
    out[((size_t)b * T_STEPS + t) * 2 + 1] = o1;
}

extern "C" void kernel_launch(void* const* d_in, const int* in_sizes, int n_in,
                              void* d_out, int out_size, void* d_ws, size_t ws_size,
                              hipStream_t stream) {
    const float* x     = (const float*)d_in[0];
    const float* fw_W1 = (const float*)d_in[1];
    const float* fw_b1 = (const float*)d_in[2];
    const float* fw_W2 = (const float*)d_in[3];
    const float* fw_b2 = (const float*)d_in[4];
    const float* bw_W1 = (const float*)d_in[5];
    const float* bw_b1 = (const float*)d_in[6];
    const float* bw_W2 = (const float*)d_in[7];
    const float* bw_b2 = (const float*)d_in[8];
    const float* Wf1   = (const float*)d_in[9];
    const float* bf1   = (const float*)d_in[10];
    const float* Wf2   = (const float*)d_in[11];
    const float* bf2   = (const float*)d_in[12];
    const float* Wo    = (const float*)d_in[13];
    const float* bo    = (const float*)d_in[14];
    float* outp = (float*)d_out;

    // workspace: xp [300][4096][40] f16 | h2s [2][300][4096][32] f16 | bp [108*512] f16
    f16* xp  = (f16*)d_ws;
    f16* h2s = xp + (size_t)T_STEPS * BATCH * 40;          // +49,152,000
    f16* bp  = h2s + (size_t)2 * T_STEPS * BATCH * 32;     // +78,643,200

    xprep_kernel<<<(T_STEPS * BATCH * 40) / 256, 256, 0, stream>>>(x, xp);
    wprep_kernel<<<108, 64, 0, stream>>>(fw_W1, bw_W1, fw_W2, bw_W2, bp);

    dim3 gl(BATCH / 32, 2);   // (128, 2)
    lstm_fused<<<gl, 384, 0, stream>>>(xp, bp, fw_b1, bw_b1, fw_b2, bw_b2, h2s);

    fc_kernel<<<(BATCH * T_STEPS) / 256, 256, 0, stream>>>(
        h2s, Wf1, bf1, Wf2, bf2, Wo, bo, outp);
}

// Round 5
// 887.542 us; speedup vs baseline: 5.4237x; 1.4534x over previous
//
#include <hip/hip_runtime.h>

// RNN_Model: biLSTM (T=300,B=4096,D=39,H1=35,H2=30) + FC(50,40,2)
// Round 5 = round 4 + FIX: x staging used uint2 (20 halfs/row) after the 32->16 row
// shrink; must be uint4 (5 thr x 8 halfs = 40 halfs/row). Features [20,39) were zero.
//  lstm_fused: 16 rows/block x 3 waves (192thr), grid (256,2) = 512 blocks = 2 blocks/CU.
//    Merged phases: {z1(s+1) MFMA + z2(s) MFMA} | barrier | {both nonlinearities} | barrier.
//  fc: MFMA chain (60->50->40->2) per 16-row wave, 16 prebuilt B-frags, no barriers.

#define T_STEPS 300
#define DIN 39
#define H1 35
#define H2 30
#define BATCH 4096
#define FC1N 50
#define FC2N 40

#define AP_STR 104       // halfs per A-panel row (52 dwords, stride 13/quad: conflict-free b128)
#define ZR 20            // floats per z column (16 rows + 4 pad)
#define Z2OFF (144 * ZR) // z2 region offset (floats)

typedef _Float16 f16;
typedef _Float16 half8 __attribute__((ext_vector_type(8)));
typedef float floatx4 __attribute__((ext_vector_type(4)));

__device__ __forceinline__ float sigf(float x) {
    return __builtin_amdgcn_rcpf(1.0f + __expf(-x));
}
__device__ __forceinline__ float tanh_f(float x) {
    return 1.0f - 2.0f * __builtin_amdgcn_rcpf(1.0f + __expf(2.0f * x));
}

// ---------------- xprep: x[B][T][39] f32 -> xp[T][B][40] f16 (slot 39 = 0) -------------
__global__ __launch_bounds__(256) void xprep_kernel(const float* __restrict__ x,
                                                    f16* __restrict__ xp) {
    size_t idx = (size_t)blockIdx.x * 256 + threadIdx.x;   // total 300*4096*40
    int k = (int)(idx % 40);
    size_t tr = idx / 40;
    int r = (int)(tr % BATCH);
    int t = (int)(tr / BATCH);
    float v = (k < DIN) ? x[((size_t)r * T_STEPS + t) * DIN + k] : 0.0f;
    xp[idx] = (f16)v;
}

// ---------------- wprep: LSTM weight B-fragments ----------------------------------------
// frag = ((dir*2+layer)*3 + cg)*9 + tile*3 + chunk ; lane holds B[k=chunk*32+oct*8+j][n]
__global__ void wprep_kernel(const float* __restrict__ fw1, const float* __restrict__ bw1,
                             const float* __restrict__ fw2, const float* __restrict__ bw2,
                             f16* __restrict__ bp) {
    int frag = blockIdx.x;        // 0..107
    int lane = threadIdx.x;       // 0..63
    int chunk = frag % 3;
    int tile  = (frag / 3) % 3;
    int cg    = (frag / 9) % 3;
    int layer = (frag / 27) % 2;
    int dir   = frag / 54;
    const float* W = (layer == 0) ? (dir ? bw1 : fw1) : (dir ? bw2 : fw2);
    int col = cg * 48 + tile * 16 + (lane & 15);
    int g = col / 36, u = col % 36;
    for (int j = 0; j < 8; ++j) {
        int k = chunk * 32 + (lane >> 4) * 8 + j;
        float v = 0.0f;
        if (layer == 0) {
            if (u < H1) {
                int ok = -1;
                if (k < 39) ok = k;                       // x rows 0..38
                else if (k >= 40 && k < 75) ok = k - 1;   // h rows 39..73
                if (ok >= 0) v = W[ok * (4 * H1) + g * H1 + u];
            }
        } else {
            if (u < H2) {
                int ok = -1;
                if (k < 35) ok = k;                       // h1 rows 0..34
                else if (k >= 36 && k < 66) ok = k - 1;   // h2 rows 35..64
                if (ok >= 0) v = W[ok * (4 * H2) + g * H2 + u];
            }
        }
        bp[(size_t)frag * 512 + lane * 8 + j] = (f16)v;
    }
}

// ---------------- fcwprep: FC weight B-fragments ----------------------------------------
// f 0..7: fc1 (tile 0..3, chunk 0..1); 8..13: fc2 (tile 0..2); 14..15: out
__global__ void fcwprep_kernel(const float* __restrict__ Wf1, const float* __restrict__ Wf2,
                               const float* __restrict__ Wo, f16* __restrict__ fcp) {
    int f = blockIdx.x;
    int lane = threadIdx.x;
    int lm = lane & 15, oct = lane >> 4;
    for (int j = 0; j < 8; ++j) {
        float v = 0.0f;
        if (f < 8) {
            int tile = f >> 1, chunk = f & 1;
            int n = tile * 16 + lm;
            int kl = chunk * 32 + oct * 8 + j;   // LDS K: fw 0..29 | pad | bw 32..61 | pad
            int krow = (kl < 30) ? kl : ((kl >= 32 && kl < 62) ? kl - 2 : -1);
            if (n < FC1N && krow >= 0) v = Wf1[krow * FC1N + n];
        } else if (f < 14) {
            int g = f - 8, tile = g >> 1, chunk = g & 1;
            int n = tile * 16 + lm;
            int k = chunk * 32 + oct * 8 + j;
            if (n < FC2N && k < FC1N) v = Wf2[k * FC2N + n];
        } else {
            int chunk = f - 14;
            int k = chunk * 32 + oct * 8 + j;
            if (lm < 2 && k < FC2N) v = Wo[k * 2 + lm];
        }
        fcp[(size_t)f * 512 + lane * 8 + j] = (f16)v;
    }
}

// ---------------- fused 2-layer LSTM -----------------------------------------------------
__device__ __forceinline__ void mfma9(const f16* ap, int arow, const half8 bf[3][3],
                                      floatx4 C[3]) {
    half8 a0 = *(const half8*)(ap + arow);
    half8 a1 = *(const half8*)(ap + arow + 32);
    half8 a2 = *(const half8*)(ap + arow + 64);
    #pragma unroll
    for (int t = 0; t < 3; ++t) {
        C[t] = __builtin_amdgcn_mfma_f32_16x16x32_f16(a0, bf[t][0], C[t], 0, 0, 0);
        C[t] = __builtin_amdgcn_mfma_f32_16x16x32_f16(a1, bf[t][1], C[t], 0, 0, 0);
        C[t] = __builtin_amdgcn_mfma_f32_16x16x32_f16(a2, bf[t][2], C[t], 0, 0, 0);
    }
}

__global__ __launch_bounds__(192) void lstm_fused(
    const f16* __restrict__ xp, const f16* __restrict__ bp,
    const float* __restrict__ fb1, const float* __restrict__ bb1,
    const float* __restrict__ fb2, const float* __restrict__ bb2,
    f16* __restrict__ h2s)
{
    __shared__ f16 ap1[16 * AP_STR];   // L1 panel: x[0,40) | h1[40,75) | 0[75,96)
    __shared__ f16 ap2[16 * AP_STR];   // L2 panel: h1[0,35) | 0 | h2[36,66) | 0[66,96)
    __shared__ float zl[288 * ZR];     // z1 cols 0..143 | z2 cols 144..287

    const int tid = threadIdx.x;
    const int b0  = blockIdx.x * 16;
    const int dir = blockIdx.y;
    const int cg   = tid >> 6;          // wave = col group
    const int lane = tid & 63;
    const int lm = lane & 15, oct = lane >> 4;
    const float* b1 = dir ? bb1 : fb1;
    const float* b2 = dir ? bb2 : fb2;

    // persistent weight B-fragments: [layer][tile][chunk]
    half8 bf[2][3][3];
    #pragma unroll
    for (int layer = 0; layer < 2; ++layer)
        #pragma unroll
        for (int tile = 0; tile < 3; ++tile)
            #pragma unroll
            for (int chunk = 0; chunk < 3; ++chunk) {
                int frag = ((dir * 2 + layer) * 3 + cg) * 9 + tile * 3 + chunk;
                bf[layer][tile][chunk] = *(const half8*)(bp + (size_t)frag * 512 + lane * 8);
            }

    // per-tile gate-bias splats (folded into MFMA C-init)
    floatx4 zb1[3], zb2[3];
    #pragma unroll
    for (int t = 0; t < 3; ++t) {
        int col = cg * 48 + t * 16 + lm;
        int g = col / 36, u = col % 36;
        float v1 = (u < H1) ? b1[g * H1 + u] : 0.f;
        float v2 = (u < H2) ? b2[g * H2 + u] : 0.f;
        zb1[t] = (floatx4){v1, v1, v1, v1};
        zb2[t] = (floatx4){v2, v2, v2, v2};
    }

    // nonlinearity items: it = tid + 192*i -> row = it&15, u = it>>4 (u in [0,36))
    int itr[3], itu[3];
    #pragma unroll
    for (int i = 0; i < 3; ++i) { int it = tid + 192 * i; itr[i] = it & 15; itu[i] = it >> 4; }
    float c1s[3] = {0.f, 0.f, 0.f}, c2s[3] = {0.f, 0.f, 0.f};

    // zero panels (h0 = c0 = 0; zero-pad K slots)
    for (int idx = tid; idx < 16 * AP_STR; idx += 192) { ap1[idx] = (f16)0.f; ap2[idx] = (f16)0.f; }
    __syncthreads();   // zero-init complete before x(0) staging (round-2 race class)

    // stage x(0); prefetch x(1).  5 threads x uint4 (8 halfs) = 40 halfs per row.
    const int xr = tid / 5, xq = tid % 5;
    uint4 xa = make_uint4(0u, 0u, 0u, 0u);
    if (tid < 80) {
        int t0 = dir ? (T_STEPS - 1) : 0;
        *(uint4*)(ap1 + xr * AP_STR + xq * 8) =
            *(const uint4*)(xp + ((size_t)t0 * BATCH + b0 + xr) * 40 + xq * 8);
        int t1 = dir ? (T_STEPS - 2) : 1;
        xa = *(const uint4*)(xp + ((size_t)t1 * BATCH + b0 + xr) * 40 + xq * 8);
    }
    __syncthreads();

    const int arow = lm * AP_STR + oct * 8;
    const int zrb  = oct * 4;

    // prologue: z1(0) -> h1(0); stage x(1), prefetch x(2)
    {
        floatx4 C1[3] = {zb1[0], zb1[1], zb1[2]};
        mfma9(ap1, arow, bf[0], C1);
        #pragma unroll
        for (int t = 0; t < 3; ++t)
            *(floatx4*)(zl + (cg * 48 + t * 16 + lm) * ZR + zrb) = C1[t];
    }
    __syncthreads();
    if (tid < 80) {
        *(uint4*)(ap1 + xr * AP_STR + xq * 8) = xa;
        int t2 = dir ? (T_STEPS - 3) : 2;
        xa = *(const uint4*)(xp + ((size_t)t2 * BATCH + b0 + xr) * 40 + xq * 8);
    }
    #pragma unroll
    for (int i = 0; i < 3; ++i) {
        int row = itr[i], u = itu[i];
        float zi = zl[(0 * 36 + u) * ZR + row];
        float zj = zl[(1 * 36 + u) * ZR + row];
        float zf = zl[(2 * 36 + u) * ZR + row];
        float zo = zl[(3 * 36 + u) * ZR + row];
        float cc = sigf(zf + 1.0f) * c1s[i] + sigf(zi) * tanh_f(zj);
        c1s[i] = cc;
        float hh = sigf(zo) * tanh_f(cc);
        if (u < H1) { f16 hv = (f16)hh; ap1[row * AP_STR + 40 + u] = hv; ap2[row * AP_STR + u] = hv; }
    }
    __syncthreads();
    // invariant at loop entry s: ap1 = {x(s+1), h1(s)}, ap2 = {h1(s), h2(s-1)}, xa = x(s+2)

    for (int s = 0; s < T_STEPS; ++s) {
        // ---- phase A: z1(s+1) + z2(s) ----
        {
            floatx4 C1[3] = {zb1[0], zb1[1], zb1[2]};
            floatx4 C2[3] = {zb2[0], zb2[1], zb2[2]};
            mfma9(ap1, arow, bf[0], C1);
            mfma9(ap2, arow, bf[1], C2);
            #pragma unroll
            for (int t = 0; t < 3; ++t) {
                *(floatx4*)(zl + (cg * 48 + t * 16 + lm) * ZR + zrb) = C1[t];
                *(floatx4*)(zl + Z2OFF + (cg * 48 + t * 16 + lm) * ZR + zrb) = C2[t];
            }
        }
        __syncthreads();   // z ready; panel reads done

        // ---- phase B: stage x(s+2); nonlin L1 -> h1(s+1); nonlin L2 -> h2(s) ----
        if (tid < 80) {
            *(uint4*)(ap1 + xr * AP_STR + xq * 8) = xa;
            int sp = s + 3; if (sp > T_STEPS - 1) sp = T_STEPS - 1;
            int tp = dir ? (T_STEPS - 1 - sp) : sp;
            xa = *(const uint4*)(xp + ((size_t)tp * BATCH + b0 + xr) * 40 + xq * 8);
        }
        const int t_out = dir ? (T_STEPS - 1 - s) : s;
        #pragma unroll
        for (int i = 0; i < 3; ++i) {
            int row = itr[i], u = itu[i];
            // L1 -> h1(s+1)
            float zi = zl[(0 * 36 + u) * ZR + row];
            float zj = zl[(1 * 36 + u) * ZR + row];
            float zf = zl[(2 * 36 + u) * ZR + row];
            float zo = zl[(3 * 36 + u) * ZR + row];
            float cc = sigf(zf + 1.0f) * c1s[i] + sigf(zi) * tanh_f(zj);
            c1s[i] = cc;
            float hh = sigf(zo) * tanh_f(cc);
            if (u < H1) { f16 hv = (f16)hh; ap1[row * AP_STR + 40 + u] = hv; ap2[row * AP_STR + u] = hv; }
            // L2 -> h2(s)
            float yi = zl[Z2OFF + (0 * 36 + u) * ZR + row];
            float yj = zl[Z2OFF + (1 * 36 + u) * ZR + row];
            float yf = zl[Z2OFF + (2 * 36 + u) * ZR + row];
            float yo = zl[Z2OFF + (3 * 36 + u) * ZR + row];
            float dd = sigf(yf + 1.0f) * c2s[i] + sigf(yi) * tanh_f(yj);
            c2s[i] = dd;
            float gg = sigf(yo) * tanh_f(dd);
            if (u < H2) {
                f16 gv = (f16)gg;
                ap2[row * AP_STR + 36 + u] = gv;
                h2s[((size_t)(dir * BATCH + b0 + row) * T_STEPS + t_out) * 32 + u] = gv;
            }
        }
        __syncthreads();   // h writes / x stage done; z reads done
    }
}

// ---------------- FC stack via MFMA ------------------------------------------------------
// h2s layout [dir][b][t][32]; fc row rid = b*T + t -> reads AND out writes coalesced.
__global__ __launch_bounds__(256) void fc_kernel(
    const f16* __restrict__ h2s, const f16* __restrict__ fcp,
    const float* __restrict__ bf1, const float* __restrict__ bf2,
    const float* __restrict__ bo, float* __restrict__ out)
{
    __shared__ f16 apf[4][16 * 72];    // per-wave A panel, stride 72 halfs (36 dw: 2-way max)
    const int tid = threadIdx.x;
    const int wv = tid >> 6, lane = tid & 63;
    const int lm = lane & 15, oct = lane >> 4;
    const size_t rid0 = (size_t)blockIdx.x * 64 + wv * 16;
    f16* ap = apf[wv];

    half8 wf[16];
    #pragma unroll
    for (int f = 0; f < 16; ++f)
        wf[f] = *(const half8*)(fcp + (size_t)f * 512 + lane * 8);

    // stage 16 rows: K = fw h2 [0,30)+pad | bw h2 [32,62)+pad  (slots 30,31 hold finite
    // poison from the 32-stride h2s rows; their weight-frag rows are zero)
    {
        int row = lane >> 2, seg = lane & 3;
        uint4 vf = *(const uint4*)(h2s + (rid0 + row) * 32 + seg * 8);
        uint4 vb = *(const uint4*)(h2s + ((size_t)BATCH * T_STEPS + rid0 + row) * 32 + seg * 8);
        *(uint4*)(ap + row * 72 + seg * 8) = vf;
        *(uint4*)(ap + row * 72 + 32 + seg * 8) = vb;
    }

    const int ar = lm * 72 + oct * 8;
    // fc1: [16x60] @ [60x50] + relu
    {
        half8 a0 = *(const half8*)(ap + ar);
        half8 a1 = *(const half8*)(ap + ar + 32);
        floatx4 C[4];
        #pragma unroll
        for (int t = 0; t < 4; ++t) {
            int col = t * 16 + lm;
            float b = (col < FC1N) ? bf1[col] : 0.f;
            C[t] = (floatx4){b, b, b, b};
            C[t] = __builtin_amdgcn_mfma_f32_16x16x32_f16(a0, wf[t * 2 + 0], C[t], 0, 0, 0);
            C[t] = __builtin_amdgcn_mfma_f32_16x16x32_f16(a1, wf[t * 2 + 1], C[t], 0, 0, 0);
        }
        #pragma unroll
        for (int t = 0; t < 4; ++t) {
            int col = t * 16 + lm;
            #pragma unroll
            for (int r = 0; r < 4; ++r)
                ap[(oct * 4 + r) * 72 + col] = (f16)fmaxf(C[t][r], 0.f);
        }
    }
    // fc2: [16x50] @ [50x40] + relu
    {
        half8 a0 = *(const half8*)(ap + ar);
        half8 a1 = *(const half8*)(ap + ar + 32);
        floatx4 D[3];
        #pragma unroll
        for (int t = 0; t < 3; ++t) {
            int col = t * 16 + lm;
            float b = (col < FC2N) ? bf2[col] : 0.f;
            D[t] = (floatx4){b, b, b, b};
            D[t] = __builtin_amdgcn_mfma_f32_16x16x32_f16(a0, wf[8 + t * 2 + 0], D[t], 0, 0, 0);
            D[t] = __builtin_amdgcn_mfma_f32_16x16x32_f16(a1, wf[8 + t * 2 + 1], D[t], 0, 0, 0);
        }
        #pragma unroll
        for (int t = 0; t < 3; ++t) {
            int col = t * 16 + lm;
            #pragma unroll
            for (int r = 0; r < 4; ++r)
                ap[(oct * 4 + r) * 72 + col] = (f16)fmaxf(D[t][r], 0.f);
        }
    }
    // out: [16x40] @ [40x2]
    {
        half8 a0 = *(const half8*)(ap + ar);
        half8 a1 = *(const half8*)(ap + ar + 32);
        float b = (lm < 2) ? bo[lm] : 0.f;
        floatx4 E = (floatx4){b, b, b, b};
        E = __builtin_amdgcn_mfma_f32_16x16x32_f16(a0, wf[14], E, 0, 0, 0);
        E = __builtin_amdgcn_mfma_f32_16x16x32_f16(a1, wf[15], E, 0, 0, 0);
        if (lm < 2) {
            #pragma unroll
            for (int r = 0; r < 4; ++r)
                out[(rid0 + oct * 4 + r) * 2 + lm] = E[r];
        }
    }
}

extern "C" void kernel_launch(void* const* d_in, const int* in_sizes, int n_in,
                              void* d_out, int out_size, void* d_ws, size_t ws_size,
                              hipStream_t stream) {
    const float* x     = (const float*)d_in[0];
    const float* fw_W1 = (const float*)d_in[1];
    const float* fw_b1 = (const float*)d_in[2];
    const float* fw_W2 = (const float*)d_in[3];
    const float* fw_b2 = (const float*)d_in[4];
    const float* bw_W1 = (const float*)d_in[5];
    const float* bw_b1 = (const float*)d_in[6];
    const float* bw_W2 = (const float*)d_in[7];
    const float* bw_b2 = (const float*)d_in[8];
    const float* Wf1   = (const float*)d_in[9];
    const float* bf1   = (const float*)d_in[10];
    const float* Wf2   = (const float*)d_in[11];
    const float* bf2   = (const float*)d_in[12];
    const float* Wo    = (const float*)d_in[13];
    const float* bo    = (const float*)d_in[14];
    float* outp = (float*)d_out;

    // ws: xp [300][4096][40] f16 | h2s [2][4096][300][32] f16 | bp 108*512 f16 | fcp 16*512 f16
    f16* xp  = (f16*)d_ws;
    f16* h2s = xp + (size_t)T_STEPS * BATCH * 40;
    f16* bp  = h2s + (size_t)2 * BATCH * T_STEPS * 32;
    f16* fcp = bp + (size_t)108 * 512;

    xprep_kernel<<<(T_STEPS * BATCH * 40) / 256, 256, 0, stream>>>(x, xp);
    wprep_kernel<<<108, 64, 0, stream>>>(fw_W1, bw_W1, fw_W2, bw_W2, bp);
    fcwprep_kernel<<<16, 64, 0, stream>>>(Wf1, Wf2, Wo, fcp);

    dim3 gl(BATCH / 16, 2);   // (256, 2) = 512 blocks -> 2 blocks/CU
    lstm_fused<<<gl, 192, 0, stream>>>(xp, bp, fw_b1, bw_b1, fw_b2, bw_b2, h2s);

    fc_kernel<<<(BATCH * T_STEPS) / 64, 256, 0, stream>>>(
        h2s, fcp, bf1, bf2, bo, outp);
}

// Round 6
// 807.377 us; speedup vs baseline: 5.9622x; 1.0993x over previous
//
#include <hip/hip_runtime.h>

// RNN_Model: biLSTM (T=300,B=4096,D=39,H1=35,H2=30) + FC(50,40,2)
// Round 6: gate-major MFMA tiling -> nonlinearity entirely in C-registers.
//  lstm_fused: 16 rows/block x 3 waves, grid (256,2) = 2 blocks/CU.
//    wave ug owns units ug*16..+15; its 4 tiles = the 4 gates of those units,
//    so each lane holds zi,zj,zf,zo of one unit in C regs -> no z LDS round-trip,
//    c-state in regs, double-buffered A panels, ONE barrier per step.
//    x staged fp32->f16 on the fly (xprep kernel eliminated); loads issued a
//    full phase ahead of use.
//  fc: MFMA chain, 64 rows/wave (4 row-groups reuse the 16 weight frags).

#define T_STEPS 300
#define DIN 39
#define H1 35
#define H2 30
#define BATCH 4096
#define FC1N 50
#define FC2N 40

#define AP_STR 104       // halfs per A-panel row (52 dwords; rows 16B-aligned for b128)

typedef _Float16 f16;
typedef _Float16 half8 __attribute__((ext_vector_type(8)));
typedef float floatx4 __attribute__((ext_vector_type(4)));

__device__ __forceinline__ float sigf(float x) {
    return __builtin_amdgcn_rcpf(1.0f + __expf(-x));
}
__device__ __forceinline__ float tanh_f(float x) {
    return 1.0f - 2.0f * __builtin_amdgcn_rcpf(1.0f + __expf(2.0f * x));
}

// ---------------- wprep: LSTM weight B-fragments, gate-major ----------------------------
// frag = dir*60 + (layer==0 ? ug*12+g*3+c : 36 + ug*12+g*3+c)
// B cols = units ug*16+0..15 of gate g; K rows: L1 x[0,40)|h1[40,75); L2 h1[0,35)|h2[35,65)
__global__ void wprep_kernel(const float* __restrict__ fw1, const float* __restrict__ bw1,
                             const float* __restrict__ fw2, const float* __restrict__ bw2,
                             f16* __restrict__ bp) {
    int frag = blockIdx.x;        // 0..119
    int lane = threadIdx.x;       // 0..63
    int dir = frag / 60;
    int rem = frag % 60;
    int layer = (rem < 36) ? 0 : 1;
    int r2 = (layer == 0) ? rem : rem - 36;
    int ug = r2 / 12, g = (r2 % 12) / 3, c = r2 % 3;
    int u = ug * 16 + (lane & 15);
    const float* W = (layer == 0) ? (dir ? bw1 : fw1) : (dir ? bw2 : fw2);
    for (int j = 0; j < 8; ++j) {
        int k = c * 32 + (lane >> 4) * 8 + j;
        float v = 0.0f;
        if (layer == 0) {
            if (u < H1) {
                int kr = (k < 39) ? k : ((k >= 40 && k < 75) ? k - 1 : -1);
                if (kr >= 0) v = W[kr * (4 * H1) + g * H1 + u];
            }
        } else {
            if (u < H2 && k < 65) v = W[k * (4 * H2) + g * H2 + u];
        }
        bp[(size_t)frag * 512 + lane * 8 + j] = (f16)v;
    }
}

// ---------------- fcwprep: FC weight B-fragments ----------------------------------------
// f 0..7: fc1 (tile 0..3, chunk 0..1); 8..13: fc2 (tile 0..2); 14..15: out
__global__ void fcwprep_kernel(const float* __restrict__ Wf1, const float* __restrict__ Wf2,
                               const float* __restrict__ Wo, f16* __restrict__ fcp) {
    int f = blockIdx.x;
    int lane = threadIdx.x;
    int lm = lane & 15, oct = lane >> 4;
    for (int j = 0; j < 8; ++j) {
        float v = 0.0f;
        if (f < 8) {
            int tile = f >> 1, chunk = f & 1;
            int n = tile * 16 + lm;
            int kl = chunk * 32 + oct * 8 + j;   // LDS K: fw 0..29 | pad | bw 32..61 | pad
            int krow = (kl < 30) ? kl : ((kl >= 32 && kl < 62) ? kl - 2 : -1);
            if (n < FC1N && krow >= 0) v = Wf1[krow * FC1N + n];
        } else if (f < 14) {
            int g = f - 8, tile = g >> 1, chunk = g & 1;
            int n = tile * 16 + lm;
            int k = chunk * 32 + oct * 8 + j;
            if (n < FC2N && k < FC1N) v = Wf2[k * FC2N + n];
        } else {
            int chunk = f - 14;
            int k = chunk * 32 + oct * 8 + j;
            if (lm < 2 && k < FC2N) v = Wo[k * 2 + lm];
        }
        fcp[(size_t)f * 512 + lane * 8 + j] = (f16)v;
    }
}

// ---------------- fused 2-layer LSTM -----------------------------------------------------
__global__ __launch_bounds__(192, 2) void lstm_fused(
    const float* __restrict__ x, const f16* __restrict__ bp,
    const float* __restrict__ fb1, const float* __restrict__ bb1,
    const float* __restrict__ fb2, const float* __restrict__ bb2,
    f16* __restrict__ h2s)
{
    __shared__ f16 pan1[2][16 * AP_STR];  // L1: x[0,40) | h1[40,75) | 0[75,96)
    __shared__ f16 pan2[2][16 * AP_STR];  // L2: h1[0,35) | h2[35,65) | 0[65,96)

    const int tid = threadIdx.x;
    const int b0  = blockIdx.x * 16;
    const int dir = blockIdx.y;
    const int wv   = tid >> 6;            // = unit group
    const int lane = tid & 63;
    const int lm = lane & 15, oct = lane >> 4;
    const float* b1 = dir ? bb1 : fb1;
    const float* b2 = dir ? bb2 : fb2;
    const int u1 = wv * 16 + lm;          // this lane's unit (L1 and L2)

    // persistent gate-major B-fragments
    half8 bf1[4][3], bf2[4][3];
    #pragma unroll
    for (int g = 0; g < 4; ++g)
        #pragma unroll
        for (int c = 0; c < 3; ++c)
            bf1[g][c] = *(const half8*)(bp + (size_t)(dir * 60 + wv * 12 + g * 3 + c) * 512 + lane * 8);
    if (wv < 2) {
        #pragma unroll
        for (int g = 0; g < 4; ++g)
            #pragma unroll
            for (int c = 0; c < 3; ++c)
                bf2[g][c] = *(const half8*)(bp + (size_t)(dir * 60 + 36 + wv * 12 + g * 3 + c) * 512 + lane * 8);
    }

    // gate biases (C-init)
    float zb1[4], zb2[4];
    #pragma unroll
    for (int g = 0; g < 4; ++g) {
        zb1[g] = (u1 < H1) ? b1[g * H1 + u1] : 0.f;
        zb2[g] = (wv < 2 && u1 < H2) ? b2[g * H2 + u1] : 0.f;
    }
    float c1[4] = {0.f, 0.f, 0.f, 0.f};   // c-state, rows oct*4+r of unit u1
    float c2[4] = {0.f, 0.f, 0.f, 0.f};

    // zero all panel buffers (h0 = c0 = 0, pads)
    for (int idx = tid; idx < 16 * AP_STR; idx += 192) {
        pan1[0][idx] = (f16)0.f; pan1[1][idx] = (f16)0.f;
        pan2[0][idx] = (f16)0.f; pan2[1][idx] = (f16)0.f;
    }
    __syncthreads();   // zero-init before x staging (round-2 race class)

    // x staging: 160 threads, thread -> (row sr, quad sq), 4 f32 loads -> 4 f16
    const int sr = tid / 10, sq = tid % 10;
    float xv[4] = {0.f, 0.f, 0.f, 0.f};
    if (tid < 160) {
        int t0 = dir ? (T_STEPS - 1) : 0;
        const float* p0 = x + ((size_t)(b0 + sr) * T_STEPS + t0) * DIN;
        union { f16 h[4]; uint2 u; } pk;
        #pragma unroll
        for (int i = 0; i < 4; ++i) { int k = sq * 4 + i; pk.h[i] = (k < DIN) ? (f16)p0[k] : (f16)0.f; }
        *(uint2*)(&pan1[0][sr * AP_STR + sq * 4]) = pk.u;
        int t1 = dir ? (T_STEPS - 2) : 1;
        const float* p1 = x + ((size_t)(b0 + sr) * T_STEPS + t1) * DIN;
        #pragma unroll
        for (int i = 0; i < 4; ++i) { int k = sq * 4 + i; xv[i] = (k < DIN) ? p1[k] : 0.f; }
    }
    __syncthreads();

    const int arow = lm * AP_STR + oct * 8;

    // prologue: z1(0) -> h1(0) into pan1[1], pan2[1]; stage x(1); load x(2)
    {
        floatx4 C[4];
        #pragma unroll
        for (int g = 0; g < 4; ++g) C[g] = (floatx4){zb1[g], zb1[g], zb1[g], zb1[g]};
        half8 a0 = *(const half8*)(&pan1[0][arow]);
        half8 a1 = *(const half8*)(&pan1[0][arow + 32]);
        half8 a2 = *(const half8*)(&pan1[0][arow + 64]);
        #pragma unroll
        for (int g = 0; g < 4; ++g) {
            C[g] = __builtin_amdgcn_mfma_f32_16x16x32_f16(a0, bf1[g][0], C[g], 0, 0, 0);
            C[g] = __builtin_amdgcn_mfma_f32_16x16x32_f16(a1, bf1[g][1], C[g], 0, 0, 0);
            C[g] = __builtin_amdgcn_mfma_f32_16x16x32_f16(a2, bf1[g][2], C[g], 0, 0, 0);
        }
        #pragma unroll
        for (int r = 0; r < 4; ++r) {
            float cc = sigf(C[2][r] + 1.0f) * c1[r] + sigf(C[0][r]) * tanh_f(C[1][r]);
            c1[r] = cc;
            float hh = sigf(C[3][r]) * tanh_f(cc);
            if (u1 < H1) {
                int row = oct * 4 + r;
                f16 hv = (f16)hh;
                pan1[1][row * AP_STR + 40 + u1] = hv;
                pan2[1][row * AP_STR + u1] = hv;
            }
        }
    }
    if (tid < 160) {
        union { f16 h[4]; uint2 u; } pk;
        #pragma unroll
        for (int i = 0; i < 4; ++i) pk.h[i] = (f16)xv[i];
        *(uint2*)(&pan1[1][sr * AP_STR + sq * 4]) = pk.u;
        int t2 = dir ? (T_STEPS - 3) : 2;
        const float* p2 = x + ((size_t)(b0 + sr) * T_STEPS + t2) * DIN;
        #pragma unroll
        for (int i = 0; i < 4; ++i) { int k = sq * 4 + i; xv[i] = (k < DIN) ? p2[k] : 0.f; }
    }
    __syncthreads();
    // invariant at iter s: pan1[p]={x(s+1),h1(s)}, pan2[p]={h1(s),h2(s-1)}, xv=x(s+2)

    for (int s = 0; s < T_STEPS; ++s) {
        const int p = 1 - (s & 1);

        // issue next x loads early (x(s+3), clamped)
        float xn[4] = {0.f, 0.f, 0.f, 0.f};
        if (tid < 160) {
            int sp = s + 3; if (sp > T_STEPS - 1) sp = T_STEPS - 1;
            int tp = dir ? (T_STEPS - 1 - sp) : sp;
            const float* px = x + ((size_t)(b0 + sr) * T_STEPS + tp) * DIN;
            #pragma unroll
            for (int i = 0; i < 4; ++i) { int k = sq * 4 + i; xn[i] = (k < DIN) ? px[k] : 0.f; }
        }

        // ---- MFMA: z1(s+1) (all waves) + z2(s) (waves 0,1) ----
        floatx4 C1g[4], C2g[4];
        #pragma unroll
        for (int g = 0; g < 4; ++g) C1g[g] = (floatx4){zb1[g], zb1[g], zb1[g], zb1[g]};
        {
            half8 a0 = *(const half8*)(&pan1[p][arow]);
            half8 a1 = *(const half8*)(&pan1[p][arow + 32]);
            half8 a2 = *(const half8*)(&pan1[p][arow + 64]);
            #pragma unroll
            for (int g = 0; g < 4; ++g) {
                C1g[g] = __builtin_amdgcn_mfma_f32_16x16x32_f16(a0, bf1[g][0], C1g[g], 0, 0, 0);
                C1g[g] = __builtin_amdgcn_mfma_f32_16x16x32_f16(a1, bf1[g][1], C1g[g], 0, 0, 0);
                C1g[g] = __builtin_amdgcn_mfma_f32_16x16x32_f16(a2, bf1[g][2], C1g[g], 0, 0, 0);
            }
        }
        if (wv < 2) {
            #pragma unroll
            for (int g = 0; g < 4; ++g) C2g[g] = (floatx4){zb2[g], zb2[g], zb2[g], zb2[g]};
            half8 a0 = *(const half8*)(&pan2[p][arow]);
            half8 a1 = *(const half8*)(&pan2[p][arow + 32]);
            half8 a2 = *(const half8*)(&pan2[p][arow + 64]);
            #pragma unroll
            for (int g = 0; g < 4; ++g) {
                C2g[g] = __builtin_amdgcn_mfma_f32_16x16x32_f16(a0, bf2[g][0], C2g[g], 0, 0, 0);
                C2g[g] = __builtin_amdgcn_mfma_f32_16x16x32_f16(a1, bf2[g][1], C2g[g], 0, 0, 0);
                C2g[g] = __builtin_amdgcn_mfma_f32_16x16x32_f16(a2, bf2[g][2], C2g[g], 0, 0, 0);
            }
        }

        // ---- nonlinearity in registers; write h into panels [1-p] ----
        f16* w1 = &pan1[1 - p][0];
        f16* w2 = &pan2[1 - p][0];
        #pragma unroll
        for (int r = 0; r < 4; ++r) {
            float cc = sigf(C1g[2][r] + 1.0f) * c1[r] + sigf(C1g[0][r]) * tanh_f(C1g[1][r]);
            c1[r] = cc;
            float hh = sigf(C1g[3][r]) * tanh_f(cc);
            if (u1 < H1) {
                int row = oct * 4 + r;
                f16 hv = (f16)hh;
                w1[row * AP_STR + 40 + u1] = hv;
                w2[row * AP_STR + u1] = hv;
            }
        }
        const int t_out = dir ? (T_STEPS - 1 - s) : s;
        if (wv < 2) {
            #pragma unroll
            for (int r = 0; r < 4; ++r) {
                float dd = sigf(C2g[2][r] + 1.0f) * c2[r] + sigf(C2g[0][r]) * tanh_f(C2g[1][r]);
                c2[r] = dd;
                float gg = sigf(C2g[3][r]) * tanh_f(dd);
                if (u1 < H2) {
                    int row = oct * 4 + r;
                    f16 gv = (f16)gg;
                    w2[row * AP_STR + 35 + u1] = gv;
                    h2s[((size_t)(dir * BATCH + b0 + row) * T_STEPS + t_out) * 32 + u1] = gv;
                }
            }
        }

        // ---- stage x(s+2) into pan1[1-p] ----
        if (tid < 160) {
            union { f16 h[4]; uint2 u; } pk;
            #pragma unroll
            for (int i = 0; i < 4; ++i) pk.h[i] = (f16)xv[i];
            *(uint2*)(&pan1[1 - p][sr * AP_STR + sq * 4]) = pk.u;
            #pragma unroll
            for (int i = 0; i < 4; ++i) xv[i] = xn[i];
        }
        __syncthreads();   // the single per-step barrier
    }
}

// ---------------- FC stack via MFMA, 64 rows per wave ------------------------------------
// h2s layout [dir][b][t][32]; rid = b*T + t -> reads AND out writes coalesced.
__global__ __launch_bounds__(256) void fc_kernel(
    const f16* __restrict__ h2s, const f16* __restrict__ fcp,
    const float* __restrict__ bf1, const float* __restrict__ bf2,
    const float* __restrict__ bo, float* __restrict__ out)
{
    __shared__ f16 apf[4][16 * 72];    // per-wave A panel, stride 72 halfs
    const int tid = threadIdx.x;
    const int wv = tid >> 6, lane = tid & 63;
    const int lm = lane & 15, oct = lane >> 4;
    f16* ap = apf[wv];

    half8 wf[16];
    #pragma unroll
    for (int f = 0; f < 16; ++f)
        wf[f] = *(const half8*)(fcp + (size_t)f * 512 + lane * 8);

    const int ar = lm * 72 + oct * 8;

    for (int it = 0; it < 4; ++it) {
        const size_t rid0 = (size_t)blockIdx.x * 256 + wv * 64 + it * 16;

        // stage 16 rows: K = fw h2 [0,30)+pad | bw h2 [32,62)+pad (pad rows: poison x 0-frag)
        {
            int row = lane >> 2, seg = lane & 3;
            uint4 vf = *(const uint4*)(h2s + (rid0 + row) * 32 + seg * 8);
            uint4 vb = *(const uint4*)(h2s + ((size_t)BATCH * T_STEPS + rid0 + row) * 32 + seg * 8);
            *(uint4*)(ap + row * 72 + seg * 8) = vf;
            *(uint4*)(ap + row * 72 + 32 + seg * 8) = vb;
        }

        // fc1: [16x60] @ [60x50] + relu
        {
            half8 a0 = *(const half8*)(ap + ar);
            half8 a1 = *(const half8*)(ap + ar + 32);
            floatx4 C[4];
            #pragma unroll
            for (int t = 0; t < 4; ++t) {
                int col = t * 16 + lm;
                float b = (col < FC1N) ? bf1[col] : 0.f;
                C[t] = (floatx4){b, b, b, b};
                C[t] = __builtin_amdgcn_mfma_f32_16x16x32_f16(a0, wf[t * 2 + 0], C[t], 0, 0, 0);
                C[t] = __builtin_amdgcn_mfma_f32_16x16x32_f16(a1, wf[t * 2 + 1], C[t], 0, 0, 0);
            }
            #pragma unroll
            for (int t = 0; t < 4; ++t) {
                int col = t * 16 + lm;
                #pragma unroll
                for (int r = 0; r < 4; ++r)
                    ap[(oct * 4 + r) * 72 + col] = (f16)fmaxf(C[t][r], 0.f);
            }
        }
        // fc2: [16x50] @ [50x40] + relu
        {
            half8 a0 = *(const half8*)(ap + ar);
            half8 a1 = *(const half8*)(ap + ar + 32);
            floatx4 D[3];
            #pragma unroll
            for (int t = 0; t < 3; ++t) {
                int col = t * 16 + lm;
                float b = (col < FC2N) ? bf2[col] : 0.f;
                D[t] = (floatx4){b, b, b, b};
                D[t] = __builtin_amdgcn_mfma_f32_16x16x32_f16(a0, wf[8 + t * 2 + 0], D[t], 0, 0, 0);
                D[t] = __builtin_amdgcn_mfma_f32_16x16x32_f16(a1, wf[8 + t * 2 + 1], D[t], 0, 0, 0);
            }
            #pragma unroll
            for (int t = 0; t < 3; ++t) {
                int col = t * 16 + lm;
                #pragma unroll
                for (int r = 0; r < 4; ++r)
                    ap[(oct * 4 + r) * 72 + col] = (f16)fmaxf(D[t][r], 0.f);
            }
        }
        // out: [16x40] @ [40x2]
        {
            half8 a0 = *(const half8*)(ap + ar);
            half8 a1 = *(const half8*)(ap + ar + 32);
            float b = (lm < 2) ? bo[lm] : 0.f;
            floatx4 E = (floatx4){b, b, b, b};
            E = __builtin_amdgcn_mfma_f32_16x16x32_f16(a0, wf[14], E, 0, 0, 0);
            E = __builtin_amdgcn_mfma_f32_16x16x32_f16(a1, wf[15], E, 0, 0, 0);
            if (lm < 2) {
                #pragma unroll
                for (int r = 0; r < 4; ++r)
                    out[(rid0 + oct * 4 + r) * 2 + lm] = E[r];
            }
        }
    }
}

extern "C" void kernel_launch(void* const* d_in, const int* in_sizes, int n_in,
                              void* d_out, int out_size, void* d_ws, size_t ws_size,
                              hipStream_t stream) {
    const float* x     = (const float*)d_in[0];
    const float* fw_W1 = (const float*)d_in[1];
    const float* fw_b1 = (const float*)d_in[2];
    const float* fw_W2 = (const float*)d_in[3];
    const float* fw_b2 = (const float*)d_in[4];
    const float* bw_W1 = (const float*)d_in[5];
    const float* bw_b1 = (const float*)d_in[6];
    const float* bw_W2 = (const float*)d_in[7];
    const float* bw_b2 = (const float*)d_in[8];
    const float* Wf1   = (const float*)d_in[9];
    const float* bf1   = (const float*)d_in[10];
    const float* Wf2   = (const float*)d_in[11];
    const float* bf2   = (const float*)d_in[12];
    const float* Wo    = (const float*)d_in[13];
    const float* bo    = (const float*)d_in[14];
    float* outp = (float*)d_out;

    // ws: h2s [2][4096][300][32] f16 | bp 120*512 f16 | fcp 16*512 f16
    f16* h2s = (f16*)d_ws;
    f16* bp  = h2s + (size_t)2 * BATCH * T_STEPS * 32;
    f16* fcp = bp + (size_t)120 * 512;

    wprep_kernel<<<120, 64, 0, stream>>>(fw_W1, bw_W1, fw_W2, bw_W2, bp);
    fcwprep_kernel<<<16, 64, 0, stream>>>(Wf1, Wf2, Wo, fcp);

    dim3 gl(BATCH / 16, 2);   // (256, 2) = 512 blocks -> 2 blocks/CU
    lstm_fused<<<gl, 192, 0, stream>>>(x, bp, fw_b1, bw_b1, fw_b2, bw_b2, h2s);

    fc_kernel<<<(BATCH * T_STEPS) / 256, 256, 0, stream>>>(
        h2s, fcp, bf1, bf2, bo, outp);
}